// Round 15
// baseline (305.791 us; speedup 1.0000x reference)
//
#include <hip/hip_runtime.h>
#include <hip/hip_bf16.h>

#define N_ATOMS 512
#define CDIM 64
#define NSIG 16384
#define KS 4
#define NBINS 33
#define NS_BLK 8    // signals per fused block (4 waves; wave = 128 atoms in GEMM, 2 signals in OMP)
#define NBLOCKS (NSIG / NS_BLK)

// ws layout (floats): [0,32768) Dn[c][n] ; [32768,65536) DnT[n][c] ;
// [65536,327680) G[n][n] ; [327680,344064) per-signal loss partials ;
// [344064] done-counter (uint)
#define WS_DN   0
#define WS_DNT  32768
#define WS_G    65536
#define WS_PART 327680
#define WS_CNT  344064

__global__ void k_normalize(const float* __restrict__ dict,
                            float* __restrict__ Dn, float* __restrict__ DnT,
                            unsigned* __restrict__ cnt) {
    const int n = blockIdx.x;    // atom/column
    const int c = threadIdx.x;   // channel/row (64 threads = 1 wave)
    if (n == 0 && c == 0) *cnt = 0;   // reset last-block counter (ws is poisoned)
    float v = dict[c * N_ATOMS + n];
    float sq = v * v;
    #pragma unroll
    for (int off = 32; off > 0; off >>= 1) sq += __shfl_down(sq, off);
    sq = __shfl(sq, 0);
    float m = fmaxf(sqrtf(sq), 1e-10f);
    float r = v / m;             // division to match reference exactly
    Dn[c * N_ATOMS + n] = r;
    DnT[n * CDIM + c]  = r;
}

__global__ void k_gram(const float* __restrict__ Dn, float* __restrict__ G) {
    __shared__ float sc[CDIM];
    const int i = blockIdx.x;
    const int t = threadIdx.x;
    if (t < CDIM) sc[t] = Dn[t * N_ATOMS + i];
    __syncthreads();
    for (int j = t; j < N_ATOMS; j += 256) {
        float a = 0.f;
        #pragma unroll
        for (int c = 0; c < CDIM; c++) a = fmaf(sc[c], Dn[c * N_ATOMS + j], a);
        G[i * N_ATOMS + j] = a;
    }
}

// OMP body. hrow = this signal's h_bar row in LDS (hb[j] == hrow[lane*8+j]).
// hsel from LDS (identical bits). Triangular solves use reciprocal-multiply.
__device__ __forceinline__ void omp_body(
    const float hb[8], const float* hrow, const float* __restrict__ G, int lane,
    int I[KS], float coef[KS])
{
    float h[8];
    #pragma unroll
    for (int j = 0; j < 8; j++) h[j] = hb[j];

    unsigned sel = 0;
    float L[KS][KS];
    float hsel[KS];
    float inv[KS];
    L[0][0] = 1.f; inv[0] = 1.f;

    #pragma unroll
    for (int k = 0; k < KS; k++) {
        // argmax of |where(selected, 0, h)|, first-max tie-break (lowest atom idx)
        float bv = -1.f; int bn = N_ATOMS;
        #pragma unroll
        for (int j = 0; j < 8; j++) {
            float v = (sel & (1u << j)) ? 0.f : fabsf(h[j]);
            if (v > bv) { bv = v; bn = lane * 8 + j; }
        }
        #pragma unroll
        for (int off = 32; off > 0; off >>= 1) {
            float ov = __shfl_down(bv, off);
            int   on = __shfl_down(bn, off);
            if (ov > bv || (ov == bv && on < bn)) { bv = ov; bn = on; }
        }
        const int idx = __shfl(bn, 0);
        if ((idx >> 3) == lane) sel |= 1u << (idx & 7);

        if (k > 0) {
            float w[KS - 1];
            for (int i2 = 0; i2 < k; i2++) {
                float t = G[I[i2] * N_ATOMS + idx];   // wave-uniform scalar load
                for (int j2 = 0; j2 < i2; j2++) t -= L[i2][j2] * w[j2];
                w[i2] = t * inv[i2];
            }
            float ssum = 0.f;
            for (int j2 = 0; j2 < k; j2++) ssum += w[j2] * w[j2];
            float corner = sqrtf(fmaxf(1.f - ssum, 1e-12f));
            for (int j2 = 0; j2 < k; j2++) L[k][j2] = w[j2];
            L[k][k] = corner;
            inv[k] = 1.f / corner;
        }
        I[k] = idx;
        hsel[k] = hrow[idx];               // LDS broadcast read, same bits as hb

        float y[KS];
        for (int i2 = 0; i2 <= k; i2++) {
            float t = hsel[i2];
            for (int j2 = 0; j2 < i2; j2++) t -= L[i2][j2] * y[j2];
            y[i2] = t * inv[i2];
        }
        for (int i2 = k; i2 >= 0; i2--) {
            float t = y[i2];
            for (int j2 = i2 + 1; j2 <= k; j2++) t -= L[j2][i2] * coef[j2];
            coef[i2] = t * inv[i2];
        }

        if (k < KS - 1) {
            float a[8];
            #pragma unroll
            for (int j = 0; j < 8; j++) a[j] = 0.f;
            for (int m = 0; m <= k; m++) {
                const float4* gr = (const float4*)(G + I[m] * N_ATOMS + lane * 8);
                float4 g0 = gr[0], g1 = gr[1];
                float cm = coef[m];
                a[0] = fmaf(cm, g0.x, a[0]); a[1] = fmaf(cm, g0.y, a[1]);
                a[2] = fmaf(cm, g0.z, a[2]); a[3] = fmaf(cm, g0.w, a[3]);
                a[4] = fmaf(cm, g1.x, a[4]); a[5] = fmaf(cm, g1.y, a[5]);
                a[6] = fmaf(cm, g1.z, a[6]); a[7] = fmaf(cm, g1.w, a[7]);
            }
            #pragma unroll
            for (int j = 0; j < 8; j++) h[j] = hb[j] - a[j];
        }
    }
}

// Fused (r11 structure): 8 signals/block, atom-split GEMM through LDS,
// 2 OMP signals/wave, + last-block loss reduction (replaces k_final).
__global__ __launch_bounds__(256, 8) void k_fused3(
    const float* __restrict__ z, const float* __restrict__ Dn,
    const float* __restrict__ DnT, const float* __restrict__ G,
    float* __restrict__ part, unsigned* __restrict__ cnt,
    float* __restrict__ out)
{
    __shared__ float Xs[CDIM][NS_BLK];      // [c][s] 2 KB
    __shared__ float Hs[NS_BLK][516];       // hbar tile 16.5 KB; reused for zste
    __shared__ float tk[NS_BLK][4];
    __shared__ unsigned lastflag;
    const int t = threadIdx.x;
    const int wave = t >> 6, lane = t & 63;
    const int s0 = blockIdx.x * NS_BLK;
    const int b = s0 >> 10;
    const int hw0 = s0 & 1023;

    if (t < 128) {   // coalesced z stage: c = t>>1, signals f..f+3 (f = (t&1)*4)
        const int c = t >> 1, f = (t & 1) * 4;
        float4 v = *(const float4*)(z + (b * CDIM + c) * 1024 + hw0 + f);
        Xs[c][f + 0] = v.x; Xs[c][f + 1] = v.y;
        Xs[c][f + 2] = v.z; Xs[c][f + 3] = v.w;
    }
    __syncthreads();

    {   // GEMM: wave owns atoms [wave*128, +128); lane owns 2 atoms.
        // k-ascending fmaf per (signal, atom) — bit-identical to prior rounds.
        const int n0 = wave * 128 + lane * 2;
        float acc[NS_BLK][2];
        #pragma unroll
        for (int q = 0; q < NS_BLK; q++) { acc[q][0] = 0.f; acc[q][1] = 0.f; }
        for (int k = 0; k < CDIM; k++) {
            const float2 d = *(const float2*)(Dn + k * N_ATOMS + n0);
            float4 xlo = *(const float4*)(&Xs[k][0]);
            float4 xhi = *(const float4*)(&Xs[k][4]);
            const float xs[NS_BLK] = {xlo.x, xlo.y, xlo.z, xlo.w,
                                      xhi.x, xhi.y, xhi.z, xhi.w};
            #pragma unroll
            for (int q = 0; q < NS_BLK; q++) {
                acc[q][0] = fmaf(xs[q], d.x, acc[q][0]);
                acc[q][1] = fmaf(xs[q], d.y, acc[q][1]);
            }
        }
        #pragma unroll
        for (int q = 0; q < NS_BLK; q++)
            *(float2*)(&Hs[q][n0]) = make_float2(acc[q][0], acc[q][1]);
    }
    __syncthreads();

    // OMP: wave's 2 signals.
    #pragma unroll
    for (int q = 0; q < 2; q++) {
        const int sl = wave * 2 + q;
        const int s = s0 + sl;
        const float xch = Xs[lane][sl];

        float hb[8];
        *(float4*)(&hb[0]) = *(const float4*)(&Hs[sl][lane * 8]);
        *(float4*)(&hb[4]) = *(const float4*)(&Hs[sl][lane * 8 + 4]);

        int I[KS]; float coef[KS];
        omp_body(hb, &Hs[sl][0], G, lane, I, coef);

        int tok[KS]; float cq[KS];
        #pragma unroll
        for (int j = 0; j < KS; j++) {
            float c2 = fminf(fmaxf(coef[j], -2.f), 2.f);
            float bf = (c2 + 2.f) / 4.f * 32.f;
            int bin = (int)rintf(bf);
            bin = bin < 0 ? 0 : (bin > 32 ? 32 : bin);
            cq[j] = -2.f + 0.125f * (float)bin;
            tok[j] = I[j] * NBINS + bin;
        }
        float zq = 0.f;
        #pragma unroll
        for (int j = 0; j < KS; j++)
            zq = fmaf(cq[j], DnT[I[j] * CDIM + lane], zq);

        float diff = zq - xch;
        Hs[sl][lane] = xch + (zq - xch);   // zste overlay (row sl read is done)

        float sq = diff * diff;
        #pragma unroll
        for (int off = 32; off > 0; off >>= 1) sq += __shfl_down(sq, off);
        if (lane == 0) part[s] = sq;
        if (lane < KS) tk[sl][lane] = (float)tok[lane];
    }
    __syncthreads();

    if (t < 128) {   // coalesced zste write: c = t>>1, signals f..f+3
        const int c = t >> 1, f = (t & 1) * 4;
        float4 v;
        v.x = Hs[f + 0][c]; v.y = Hs[f + 1][c];
        v.z = Hs[f + 2][c]; v.w = Hs[f + 3][c];
        *(float4*)(out + (b * CDIM + c) * 1024 + hw0 + f) = v;
    }
    if (t < NS_BLK * KS)   // 32 consecutive token floats
        out[NSIG * CDIM + 1 + s0 * KS + t] = tk[t >> 2][t & 3];

    // ---- last-block loss reduction (replaces k_final) ----
    __threadfence();                       // release part[] writes
    if (t == 0) lastflag = (atomicAdd(cnt, 1u) == NBLOCKS - 1) ? 1u : 0u;
    __syncthreads();
    if (lastflag) {
        __threadfence();                   // acquire other blocks' part[] writes
        float sum = 0.f;
        const float4* p4 = (const float4*)part;
        for (int i = t; i < NSIG / 4; i += 256) {
            float4 v = p4[i];
            sum += v.x + v.y + v.z + v.w;
        }
        #pragma unroll
        for (int off = 32; off > 0; off >>= 1) sum += __shfl_down(sum, off);
        __shared__ float red[4];
        if ((t & 63) == 0) red[t >> 6] = sum;
        __syncthreads();
        if (t == 0) {
            float v = (red[0] + red[1] + red[2] + red[3]) / 1048576.f;
            out[NSIG * CDIM] = v + 0.25f * v;
        }
    }
}

extern "C" void kernel_launch(void* const* d_in, const int* in_sizes, int n_in,
                              void* d_out, int out_size, void* d_ws, size_t ws_size,
                              hipStream_t stream) {
    const float* z    = (const float*)d_in[0];
    const float* dict = (const float*)d_in[1];
    float* out  = (float*)d_out;
    float* w    = (float*)d_ws;
    float* Dn   = w + WS_DN;
    float* DnT  = w + WS_DNT;
    float* G    = w + WS_G;
    float* part = w + WS_PART;
    unsigned* cnt = (unsigned*)(w + WS_CNT);

    hipLaunchKernelGGL(k_normalize, dim3(N_ATOMS), dim3(CDIM), 0, stream, dict, Dn, DnT, cnt);
    hipLaunchKernelGGL(k_gram,      dim3(N_ATOMS), dim3(256),  0, stream, Dn, G);
    hipLaunchKernelGGL(k_fused3,    dim3(NBLOCKS), dim3(256), 0, stream,
                       z, Dn, DnT, G, part, cnt, out);
}

// Round 16
// 120.765 us; speedup vs baseline: 2.5321x; 2.5321x over previous
//
#include <hip/hip_runtime.h>
#include <hip/hip_bf16.h>

#define N_ATOMS 512
#define CDIM 64
#define NSIG 16384
#define KS 4
#define NBINS 33
#define NS_BLK 8    // signals per fused block (4 waves; wave = 128 atoms in GEMM, 2 signals in OMP)

// ws layout (floats): [0,32768) Dn[c][n] ; [32768,65536) DnT[n][c] ;
// [65536,327680) G[n][n] ; [327680,344064) per-signal loss partials
#define WS_DN   0
#define WS_DNT  32768
#define WS_G    65536
#define WS_PART 327680

__global__ void k_normalize(const float* __restrict__ dict,
                            float* __restrict__ Dn, float* __restrict__ DnT) {
    const int n = blockIdx.x;    // atom/column
    const int c = threadIdx.x;   // channel/row (64 threads = 1 wave)
    float v = dict[c * N_ATOMS + n];
    float sq = v * v;
    #pragma unroll
    for (int off = 32; off > 0; off >>= 1) sq += __shfl_down(sq, off);
    sq = __shfl(sq, 0);
    float m = fmaxf(sqrtf(sq), 1e-10f);
    float r = v / m;             // division to match reference exactly
    Dn[c * N_ATOMS + n] = r;
    DnT[n * CDIM + c]  = r;
}

__global__ void k_gram(const float* __restrict__ Dn, float* __restrict__ G) {
    __shared__ float sc[CDIM];
    const int i = blockIdx.x;
    const int t = threadIdx.x;
    if (t < CDIM) sc[t] = Dn[t * N_ATOMS + i];
    __syncthreads();
    for (int j = t; j < N_ATOMS; j += 256) {
        float a = 0.f;
        #pragma unroll
        for (int c = 0; c < CDIM; c++) a = fmaf(sc[c], Dn[c * N_ATOMS + j], a);
        G[i * N_ATOMS + j] = a;
    }
}

// OMP body. hrow = this signal's h_bar row in LDS (hb[j] == hrow[lane*8+j]).
// hsel comes straight from LDS (identical bits). Triangular solves use
// reciprocal-multiply (inv[i] = 1/L[i][i], one divide per step instead of ~5;
// <=2 ulp difference on coef — selection/binning unaffected).
__device__ __forceinline__ void omp_body(
    const float hb[8], const float* hrow, const float* __restrict__ G, int lane,
    int I[KS], float coef[KS])
{
    float h[8];
    #pragma unroll
    for (int j = 0; j < 8; j++) h[j] = hb[j];

    unsigned sel = 0;
    float L[KS][KS];
    float hsel[KS];
    float inv[KS];
    L[0][0] = 1.f; inv[0] = 1.f;

    #pragma unroll
    for (int k = 0; k < KS; k++) {
        // argmax of |where(selected, 0, h)|, first-max tie-break (lowest atom idx)
        float bv = -1.f; int bn = N_ATOMS;
        #pragma unroll
        for (int j = 0; j < 8; j++) {
            float v = (sel & (1u << j)) ? 0.f : fabsf(h[j]);
            if (v > bv) { bv = v; bn = lane * 8 + j; }
        }
        #pragma unroll
        for (int off = 32; off > 0; off >>= 1) {
            float ov = __shfl_down(bv, off);
            int   on = __shfl_down(bn, off);
            if (ov > bv || (ov == bv && on < bn)) { bv = ov; bn = on; }
        }
        const int idx = __shfl(bn, 0);
        if ((idx >> 3) == lane) sel |= 1u << (idx & 7);

        if (k > 0) {
            float w[KS - 1];
            for (int i2 = 0; i2 < k; i2++) {
                float t = G[I[i2] * N_ATOMS + idx];   // wave-uniform scalar load
                for (int j2 = 0; j2 < i2; j2++) t -= L[i2][j2] * w[j2];
                w[i2] = t * inv[i2];
            }
            float ssum = 0.f;
            for (int j2 = 0; j2 < k; j2++) ssum += w[j2] * w[j2];
            float corner = sqrtf(fmaxf(1.f - ssum, 1e-12f));
            for (int j2 = 0; j2 < k; j2++) L[k][j2] = w[j2];
            L[k][k] = corner;
            inv[k] = 1.f / corner;
        }
        I[k] = idx;
        hsel[k] = hrow[idx];               // LDS broadcast read, same bits as hb

        float y[KS];
        for (int i2 = 0; i2 <= k; i2++) {
            float t = hsel[i2];
            for (int j2 = 0; j2 < i2; j2++) t -= L[i2][j2] * y[j2];
            y[i2] = t * inv[i2];
        }
        for (int i2 = k; i2 >= 0; i2--) {
            float t = y[i2];
            for (int j2 = i2 + 1; j2 <= k; j2++) t -= L[j2][i2] * coef[j2];
            coef[i2] = t * inv[i2];
        }

        if (k < KS - 1) {
            float a[8];
            #pragma unroll
            for (int j = 0; j < 8; j++) a[j] = 0.f;
            for (int m = 0; m <= k; m++) {
                const float4* gr = (const float4*)(G + I[m] * N_ATOMS + lane * 8);
                float4 g0 = gr[0], g1 = gr[1];
                float cm = coef[m];
                a[0] = fmaf(cm, g0.x, a[0]); a[1] = fmaf(cm, g0.y, a[1]);
                a[2] = fmaf(cm, g0.z, a[2]); a[3] = fmaf(cm, g0.w, a[3]);
                a[4] = fmaf(cm, g1.x, a[4]); a[5] = fmaf(cm, g1.y, a[5]);
                a[6] = fmaf(cm, g1.z, a[6]); a[7] = fmaf(cm, g1.w, a[7]);
            }
            #pragma unroll
            for (int j = 0; j < 8; j++) h[j] = hb[j] - a[j];
        }
    }
}

// Fused v4: 8 signals/block, atom-split GEMM through LDS, 2 interleaved OMP signals/wave.
__global__ __launch_bounds__(256, 8) void k_fused3(
    const float* __restrict__ z, const float* __restrict__ Dn,
    const float* __restrict__ DnT, const float* __restrict__ G,
    float* __restrict__ part, float* __restrict__ out)
{
    __shared__ float Xs[CDIM][NS_BLK];      // [c][s] 2 KB
    __shared__ float Hs[NS_BLK][516];       // hbar tile 16.5 KB; reused for zste
    __shared__ float tk[NS_BLK][4];
    const int t = threadIdx.x;
    const int wave = t >> 6, lane = t & 63;
    const int s0 = blockIdx.x * NS_BLK;
    const int b = s0 >> 10;
    const int hw0 = s0 & 1023;

    if (t < 128) {   // coalesced z stage: c = t>>1, signals f..f+3 (f = (t&1)*4)
        const int c = t >> 1, f = (t & 1) * 4;
        float4 v = *(const float4*)(z + (b * CDIM + c) * 1024 + hw0 + f);
        Xs[c][f + 0] = v.x; Xs[c][f + 1] = v.y;
        Xs[c][f + 2] = v.z; Xs[c][f + 3] = v.w;
    }
    __syncthreads();

    {   // GEMM: wave owns atoms [wave*128, +128); lane owns 2 atoms.
        // k-ascending fmaf per (signal, atom) — bit-identical to prior rounds.
        const int n0 = wave * 128 + lane * 2;
        float acc[NS_BLK][2];
        #pragma unroll
        for (int q = 0; q < NS_BLK; q++) { acc[q][0] = 0.f; acc[q][1] = 0.f; }
        for (int k = 0; k < CDIM; k++) {
            const float2 d = *(const float2*)(Dn + k * N_ATOMS + n0);
            float4 xlo = *(const float4*)(&Xs[k][0]);
            float4 xhi = *(const float4*)(&Xs[k][4]);
            const float xs[NS_BLK] = {xlo.x, xlo.y, xlo.z, xlo.w,
                                      xhi.x, xhi.y, xhi.z, xhi.w};
            #pragma unroll
            for (int q = 0; q < NS_BLK; q++) {
                acc[q][0] = fmaf(xs[q], d.x, acc[q][0]);
                acc[q][1] = fmaf(xs[q], d.y, acc[q][1]);
            }
        }
        #pragma unroll
        for (int q = 0; q < NS_BLK; q++)
            *(float2*)(&Hs[q][n0]) = make_float2(acc[q][0], acc[q][1]);
    }
    __syncthreads();

    // OMP: wave's 2 signals.
    #pragma unroll
    for (int q = 0; q < 2; q++) {
        const int sl = wave * 2 + q;
        const int s = s0 + sl;
        const float xch = Xs[lane][sl];

        float hb[8];
        *(float4*)(&hb[0]) = *(const float4*)(&Hs[sl][lane * 8]);
        *(float4*)(&hb[4]) = *(const float4*)(&Hs[sl][lane * 8 + 4]);

        int I[KS]; float coef[KS];
        omp_body(hb, &Hs[sl][0], G, lane, I, coef);

        int tok[KS]; float cq[KS];
        #pragma unroll
        for (int j = 0; j < KS; j++) {
            float c2 = fminf(fmaxf(coef[j], -2.f), 2.f);
            float bf = (c2 + 2.f) / 4.f * 32.f;
            int bin = (int)rintf(bf);
            bin = bin < 0 ? 0 : (bin > 32 ? 32 : bin);
            cq[j] = -2.f + 0.125f * (float)bin;
            tok[j] = I[j] * NBINS + bin;
        }
        float zq = 0.f;
        #pragma unroll
        for (int j = 0; j < KS; j++)
            zq = fmaf(cq[j], DnT[I[j] * CDIM + lane], zq);

        float diff = zq - xch;
        Hs[sl][lane] = xch + (zq - xch);   // zste overlay (row sl read is done)

        float sq = diff * diff;
        #pragma unroll
        for (int off = 32; off > 0; off >>= 1) sq += __shfl_down(sq, off);
        if (lane == 0) part[s] = sq;
        if (lane < KS) tk[sl][lane] = (float)tok[lane];
    }
    __syncthreads();

    if (t < 128) {   // coalesced zste write: c = t>>1, signals f..f+3
        const int c = t >> 1, f = (t & 1) * 4;
        float4 v;
        v.x = Hs[f + 0][c]; v.y = Hs[f + 1][c];
        v.z = Hs[f + 2][c]; v.w = Hs[f + 3][c];
        *(float4*)(out + (b * CDIM + c) * 1024 + hw0 + f) = v;
    }
    if (t < NS_BLK * KS)   // 32 consecutive token floats
        out[NSIG * CDIM + 1 + s0 * KS + t] = tk[t >> 2][t & 3];
}

__global__ __launch_bounds__(256) void k_final(const float* __restrict__ part,
                                               float* __restrict__ out) {
    __shared__ float red[4];
    const int t = threadIdx.x;
    float sum = 0.f;
    const float4* p4 = (const float4*)part;
    for (int i = t; i < NSIG / 4; i += 256) {
        float4 v = p4[i];
        sum += v.x + v.y + v.z + v.w;
    }
    #pragma unroll
    for (int off = 32; off > 0; off >>= 1) sum += __shfl_down(sum, off);
    if ((t & 63) == 0) red[t >> 6] = sum;
    __syncthreads();
    if (t == 0) {
        float v = (red[0] + red[1] + red[2] + red[3]) / 1048576.f;
        out[NSIG * CDIM] = v + 0.25f * v;
    }
}

extern "C" void kernel_launch(void* const* d_in, const int* in_sizes, int n_in,
                              void* d_out, int out_size, void* d_ws, size_t ws_size,
                              hipStream_t stream) {
    const float* z    = (const float*)d_in[0];
    const float* dict = (const float*)d_in[1];
    float* out  = (float*)d_out;
    float* w    = (float*)d_ws;
    float* Dn   = w + WS_DN;
    float* DnT  = w + WS_DNT;
    float* G    = w + WS_G;
    float* part = w + WS_PART;

    hipLaunchKernelGGL(k_normalize, dim3(N_ATOMS), dim3(CDIM), 0, stream, dict, Dn, DnT);
    hipLaunchKernelGGL(k_gram,      dim3(N_ATOMS), dim3(256),  0, stream, Dn, G);
    hipLaunchKernelGGL(k_fused3,    dim3(NSIG / NS_BLK), dim3(256), 0, stream,
                       z, Dn, DnT, G, part, out);
    hipLaunchKernelGGL(k_final,     dim3(1), dim3(256), 0, stream, part, out);
}